// Round 14
// baseline (65.038 us; speedup 1.0000x reference)
//
#include <hip/hip_runtime.h>
#include <hip/hip_bf16.h>

using bf16x8 = __attribute__((ext_vector_type(8))) short;
using f16x8  = __attribute__((ext_vector_type(8))) _Float16;
using f16x4  = __attribute__((ext_vector_type(4))) _Float16;
using f32x4  = __attribute__((ext_vector_type(4))) float;

#define THREADS   256
#define NROWS_U   300000
#define WS_NEED   (NROWS_U * 64 * 2)   // V: 300000 x 64 fp16 = 38.4 MB
#define TPM       6250                 // tiles per mode (100000/16)
#define BPM       521                  // blocks per mode: ceil(6250 / 12)
#define NB_PC     (BPM * 3)            // 1563
#define NB_MAIN   2048
#define NITERS_M  15625                // 500000 / 32

__device__ __forceinline__ short f2bf(float f) {
    __hip_bfloat16 h = __float2bfloat16(f);
    return __builtin_bit_cast(short, h);
}

__device__ __forceinline__ bf16x8 cvt8(float4 a, float4 b) {
    bf16x8 r;
    r[0] = f2bf(a.x); r[1] = f2bf(a.y); r[2] = f2bf(a.z); r[3] = f2bf(a.w);
    r[4] = f2bf(b.x); r[5] = f2bf(b.y); r[6] = f2bf(b.z); r[7] = f2bf(b.w);
    return r;
}

// ---------------- precompute: V'[r][ncol*4+nt] = (U_mode @ W1_mode)[r][nt*16+ncol], fp16 ----
// Max-occupancy variant: no LDS, no pipeline, VGPR-budgeted to 64 (8 waves/EU).
// One mode per block; 12 tiles per block (3 per wave), clamped tail (idempotent dup).
__global__ __launch_bounds__(THREADS, 8) void pc_kernel(
    const float* __restrict__ U,    // [300000,64]
    const float* __restrict__ W1,   // [193,50]
    _Float16*    __restrict__ V)    // [300000,64] permuted cols
{
    const int lane = threadIdx.x & 63;
    const int g    = lane >> 4;    // 0..3 (k-subgroup)
    const int ncol = lane & 15;    // A-row within tile / n within N-tile
    const int warp = threadIdx.x >> 6;
    const int mode = blockIdx.x / BPM;          // 0..2 (uniform per block)
    const int bloc = blockIdx.x - mode * BPM;   // 0..520

    // B-fragments for this block's mode, in 32 VGPRs.
    bf16x8 Bf[8];
    {
        const float* Wm = W1 + mode * 64 * 50;
#pragma unroll
        for (int nt = 0; nt < 4; ++nt) {
            const int n = nt * 16 + ncol;
            const bool vld = n < 50;
#pragma unroll
            for (int ks = 0; ks < 2; ++ks) {
                bf16x8 v;
#pragma unroll
                for (int j = 0; j < 8; ++j) {
                    float w = vld ? Wm[(ks * 32 + g * 8 + j) * 50 + n] : 0.f;
                    v[j] = f2bf(w);
                }
                Bf[nt * 2 + ks] = v;
            }
        }
    }

    // serial blocking loop; TLP (8 waves/EU) hides the memory latency
#pragma unroll 1
    for (int j = 0; j < 3; ++j) {
        int tl = bloc * 12 + warp * 3 + j;
        if (tl > TPM - 1) tl = TPM - 1;          // clamp: duplicate work, same data
        const int tile = mode * TPM + tl;

        const float* p = U + (size_t)(tile * 16 + ncol) * 64 + g * 8;
        float4 a0 = ((const float4*)p)[0],        a1 = ((const float4*)p)[1];
        float4 a2 = ((const float4*)(p + 32))[0], a3 = ((const float4*)(p + 32))[1];
        bf16x8 A0 = cvt8(a0, a1);
        bf16x8 A1 = cvt8(a2, a3);

        f32x4 acc[4];
#pragma unroll
        for (int nt = 0; nt < 4; ++nt) acc[nt] = (f32x4){0.f, 0.f, 0.f, 0.f};
#pragma unroll
        for (int nt = 0; nt < 4; ++nt) {
            acc[nt] = __builtin_amdgcn_mfma_f32_16x16x32_bf16(A0, Bf[nt * 2 + 0], acc[nt], 0, 0, 0);
            acc[nt] = __builtin_amdgcn_mfma_f32_16x16x32_bf16(A1, Bf[nt * 2 + 1], acc[nt], 0, 0, 0);
        }

        const int base = tile * 16;
#pragma unroll
        for (int r = 0; r < 4; ++r) {
            f16x4 pk;
#pragma unroll
            for (int nt = 0; nt < 4; ++nt) pk[nt] = (_Float16)acc[nt][r];
            *(f16x4*)(V + (size_t)(base + g * 4 + r) * 64 + ncol * 4) = pk;
        }
    }
}

// ---------------- main: gather-sum-tanh-dot over V' ----------------
__global__ __launch_bounds__(THREADS) void etl_main(
    const int*      __restrict__ bi,   // [500000,3]
    const float*    __restrict__ t,    // [500000]
    const _Float16* __restrict__ V,    // [300000,64] permuted cols
    const float*    __restrict__ W1,   // [193,50] (row 192 used)
    const float*    __restrict__ b1,   // [50]
    const float*    __restrict__ W2,   // [50]
    const float*    __restrict__ b2,   // [1]
    float*          __restrict__ out)  // [500000]
{
    const int lane = threadIdx.x & 63;
    const int r8   = lane >> 3;   // 0..7: row within 8-row group
    const int c    = lane & 7;    // 0..7: 8-wide position chunk

    // position pos = c*8+j in V' maps to original col n = (pos&3)*16 + (pos>>2)
    float w192r[8], b1r[8], w2r[8];
#pragma unroll
    for (int j = 0; j < 8; ++j) {
        int pos = c * 8 + j;
        int n = (pos & 3) * 16 + (pos >> 2);
        bool vld = n < 50;
        w192r[j] = vld ? W1[192 * 50 + n] : 0.f;
        b1r[j]   = vld ? b1[n] : 0.f;
        w2r[j]   = vld ? W2[n] : 0.f;
    }
    const float b2v = b2[0];

    const int nwaves = NB_MAIN * (THREADS / 64);
    for (int it = blockIdx.x * (THREADS / 64) + (threadIdx.x >> 6);
         it < NITERS_M; it += nwaves) {
        const int base = it * 32;   // 32 rows per wave-iteration

        int id[4][3];
#pragma unroll
        for (int u = 0; u < 4; ++u) {
            int r = base + u * 8 + r8;
#pragma unroll
            for (int m = 0; m < 3; ++m)
                id[u][m] = bi[r * 3 + m] + m * 100000;
        }

        f16x8 va[4][3];
#pragma unroll
        for (int u = 0; u < 4; ++u)
#pragma unroll
            for (int m = 0; m < 3; ++m)
                va[u][m] = *(const f16x8*)(V + (size_t)id[u][m] * 64 + c * 8);

        float tv[4];
#pragma unroll
        for (int u = 0; u < 4; ++u) tv[u] = t[base + u * 8 + r8];

#pragma unroll
        for (int u = 0; u < 4; ++u) {
            float acc = 0.f;
#pragma unroll
            for (int j = 0; j < 8; ++j) {
                float h = (float)va[u][0][j] + (float)va[u][1][j] +
                          (float)va[u][2][j] + tv[u] * w192r[j] + b1r[j];
                float e = __expf(2.f * h);
                acc += (1.f - 2.f * __builtin_amdgcn_rcpf(e + 1.f)) * w2r[j];
            }
            acc += __shfl_xor(acc, 1, 64);
            acc += __shfl_xor(acc, 2, 64);
            acc += __shfl_xor(acc, 4, 64);
            if (c == 0) out[base + u * 8 + r8] = acc + b2v;
        }
    }
}

// ---------------- fallback: direct f32 gather (ws too small) ----------------
__global__ __launch_bounds__(THREADS) void etl_f32(
    const int*   __restrict__ bi,
    const float* __restrict__ t,
    const float* __restrict__ U,
    const float* __restrict__ W1,
    const float* __restrict__ b1,
    const float* __restrict__ W2,
    const float* __restrict__ b2,
    float*       __restrict__ out)
{
    __shared__ short bsh[24][64][8];
    for (int e = threadIdx.x; e < 24 * 64; e += THREADS) {
        int f = e >> 6, l = e & 63;
        int nt = f / 6, ks = f - nt * 6;
        int n  = nt * 16 + (l & 15);
        int k0 = ks * 32 + ((l >> 4) << 3);
        bf16x8 v;
#pragma unroll
        for (int j = 0; j < 8; ++j) {
            float w = (n < 50) ? W1[(k0 + j) * 50 + n] : 0.f;
            v[j] = f2bf(w);
        }
        *(bf16x8*)(&bsh[f][l][0]) = v;
    }
    __syncthreads();

    const int lane = threadIdx.x & 63;
    const int g    = lane >> 4;
    const int ncol = lane & 15;

    bf16x8 Bf[24];
#pragma unroll
    for (int f = 0; f < 24; ++f) Bf[f] = *(const bf16x8*)(&bsh[f][lane][0]);

    float w192[4], b1r[4], w2r[4];
#pragma unroll
    for (int nt = 0; nt < 4; ++nt) {
        int n = nt * 16 + ncol;
        bool vld = (n < 50);
        w192[nt] = vld ? W1[192 * 50 + n] : 0.f;
        b1r[nt]  = vld ? b1[n] : 0.f;
        w2r[nt]  = vld ? W2[n] : 0.f;
    }
    const float b2v = b2[0];

    const int nwaves = 768 * (THREADS / 64);
    const int wid    = blockIdx.x * (THREADS / 64) + (threadIdx.x >> 6);

    for (int tile = wid; tile < 31250; tile += nwaves) {
        const int base = tile * 16;
        const int row  = base + ncol;
        int i0 = bi[row * 3 + 0];
        int i1 = bi[row * 3 + 1] + 100000;
        int i2 = bi[row * 3 + 2] + 200000;

        bf16x8 A[6];
        const float* p0 = U + (size_t)i0 * 64 + g * 8;
        const float* p1 = U + (size_t)i1 * 64 + g * 8;
        const float* p2 = U + (size_t)i2 * 64 + g * 8;
        A[0] = cvt8(((const float4*)p0)[0], ((const float4*)p0)[1]);
        A[1] = cvt8(((const float4*)(p0 + 32))[0], ((const float4*)(p0 + 32))[1]);
        A[2] = cvt8(((const float4*)p1)[0], ((const float4*)p1)[1]);
        A[3] = cvt8(((const float4*)(p1 + 32))[0], ((const float4*)(p1 + 32))[1]);
        A[4] = cvt8(((const float4*)p2)[0], ((const float4*)p2)[1]);
        A[5] = cvt8(((const float4*)(p2 + 32))[0], ((const float4*)(p2 + 32))[1]);

        f32x4 acc[4];
#pragma unroll
        for (int nt = 0; nt < 4; ++nt) acc[nt] = (f32x4){0.f, 0.f, 0.f, 0.f};
#pragma unroll
        for (int ks = 0; ks < 6; ++ks) {
#pragma unroll
            for (int nt = 0; nt < 4; ++nt) {
                acc[nt] = __builtin_amdgcn_mfma_f32_16x16x32_bf16(
                    A[ks], Bf[nt * 6 + ks], acc[nt], 0, 0, 0);
            }
        }

        float4 tv = *(const float4*)(t + base + g * 4);
        float tarr[4] = {tv.x, tv.y, tv.z, tv.w};
        float part[4] = {0.f, 0.f, 0.f, 0.f};
#pragma unroll
        for (int nt = 0; nt < 4; ++nt) {
#pragma unroll
            for (int r = 0; r < 4; ++r) {
                float pre = acc[nt][r] + tarr[r] * w192[nt] + b1r[nt];
                float e  = __expf(2.f * pre);
                float h  = 1.f - 2.f * __builtin_amdgcn_rcpf(e + 1.f);
                part[r] += h * w2r[nt];
            }
        }
#pragma unroll
        for (int r = 0; r < 4; ++r) {
#pragma unroll
            for (int m = 1; m < 16; m <<= 1)
                part[r] += __shfl_xor(part[r], m, 64);
        }
        if (ncol == 0) {
            float4 o = make_float4(part[0] + b2v, part[1] + b2v,
                                   part[2] + b2v, part[3] + b2v);
            *(float4*)(out + base + g * 4) = o;
        }
    }
}

extern "C" void kernel_launch(void* const* d_in, const int* in_sizes, int n_in,
                              void* d_out, int out_size, void* d_ws, size_t ws_size,
                              hipStream_t stream) {
    const int*   bi = (const int*)  d_in[0];
    const float* t  = (const float*)d_in[1];
    const float* U  = (const float*)d_in[2];
    const float* W1 = (const float*)d_in[3];
    const float* b1 = (const float*)d_in[4];
    const float* W2 = (const float*)d_in[5];
    const float* b2 = (const float*)d_in[6];
    float* out = (float*)d_out;

    if (ws_size >= (size_t)WS_NEED) {
        _Float16* V = (_Float16*)d_ws;
        pc_kernel<<<NB_PC, THREADS, 0, stream>>>(U, W1, V);
        etl_main<<<NB_MAIN, THREADS, 0, stream>>>(bi, t, V, W1, b1, W2, b2, out);
    } else {
        etl_f32<<<768, THREADS, 0, stream>>>(bi, t, U, W1, b1, W2, b2, out);
    }
}

// Round 15
// 55.682 us; speedup vs baseline: 1.1680x; 1.1680x over previous
//
#include <hip/hip_runtime.h>
#include <hip/hip_bf16.h>

using bf16x8 = __attribute__((ext_vector_type(8))) short;
using f16x8  = __attribute__((ext_vector_type(8))) _Float16;
using f16x4  = __attribute__((ext_vector_type(4))) _Float16;
using f32x4  = __attribute__((ext_vector_type(4))) float;

#define THREADS   256
#define NROWS_U   300000
#define WS_NEED   (NROWS_U * 64 * 2)   // V: 300000 x 64 fp16 = 38.4 MB
#define TPM       6250                 // tiles per mode (100000/16)
#define TPB       16                   // tiles per block (4 per wave)
#define BPM       391                  // ceil(6250/16)
#define NB_PC     (BPM * 3)            // 1173
#define NB_MAIN   2048
#define NITERS_M  15625                // 500000 / 32

__device__ __forceinline__ short f2bf(float f) {
    __hip_bfloat16 h = __float2bfloat16(f);
    return __builtin_bit_cast(short, h);
}

__device__ __forceinline__ bf16x8 cvt8(float4 a, float4 b) {
    bf16x8 r;
    r[0] = f2bf(a.x); r[1] = f2bf(a.y); r[2] = f2bf(a.z); r[3] = f2bf(a.w);
    r[4] = f2bf(b.x); r[5] = f2bf(b.y); r[6] = f2bf(b.z); r[7] = f2bf(b.w);
    return r;
}

__device__ __forceinline__ float4 tof4(f32x4 v) {
    return make_float4(v[0], v[1], v[2], v[3]);
}

// ---------------- precompute: V'[r][ncol*4+nt] = (U_mode @ W1_mode)[r][nt*16+ncol], fp16 ----
// m97-style: global_load_lds staging (pre-swizzled source), double-buffered per-wave LDS,
// counted vmcnt pipeline, MFMA from swizzled ds_read_b128, packed f16x4 stores.
__global__ __launch_bounds__(THREADS, 6) void pc_kernel(
    const float* __restrict__ U,    // [300000,64]
    const float* __restrict__ W1,   // [193,50]
    _Float16*    __restrict__ V)    // [300000,64] permuted cols
{
    __shared__ __align__(16) float gb[4][2][1024];  // 32KB: [warp][buf][16rows x 64f]

    const int lane = threadIdx.x & 63;
    const int g    = lane >> 4;    // 0..3 (k-subgroup)
    const int ncol = lane & 15;    // A-row within tile / n within N-tile
    const int warp = threadIdx.x >> 6;
    const int mode = blockIdx.x / BPM;
    const int bloc = blockIdx.x % BPM;

    const int srow = lane >> 4;    // staging row-subgroup
    const int schk = lane & 15;    // staging chunk

    // clamped global tile index for this wave's j-th tile
    auto tileof = [&](int j) {
        int tl = bloc * TPB + warp * 4 + j;
        if (tl > TPM - 1) tl = TPM - 1;
        return mode * TPM + tl;
    };

    // stage tile j into buffer b: 4 x global_load_lds(16B), source pre-swizzled
    // LDS[row][x] <- global chunk (row, x^row); dense 256B/row segments preserved.
    auto stage = [&](int j, int b) {
        const int tile = tileof(j);
#pragma unroll
        for (int q = 0; q < 4; ++q) {
            const int row = q * 4 + srow;
            const float* gp = U + (size_t)(tile * 16 + row) * 64 + ((schk ^ row) << 2);
            __builtin_amdgcn_global_load_lds(
                (const __attribute__((address_space(1))) void*)gp,
                (__attribute__((address_space(3))) void*)(&gb[warp][b][q * 256]),
                16, 0, 0);
        }
    };

    // prologue: issue staging for tiles 0,1 FIRST (their latency hides Bf setup)
    stage(0, 0);
    stage(1, 1);

    // B-fragments for this block's mode, in 32 VGPRs (same as R14)
    bf16x8 Bf[8];
    {
        const float* Wm = W1 + mode * 64 * 50;
#pragma unroll
        for (int nt = 0; nt < 4; ++nt) {
            const int n = nt * 16 + ncol;
            const bool vld = n < 50;
#pragma unroll
            for (int ks = 0; ks < 2; ++ks) {
                bf16x8 v;
#pragma unroll
                for (int jj = 0; jj < 8; ++jj) {
                    float w = vld ? Wm[(ks * 32 + g * 8 + jj) * 50 + n] : 0.f;
                    v[jj] = f2bf(w);
                }
                Bf[nt * 2 + ks] = v;
            }
        }
    }

    const f32x4* lb0 = (const f32x4*)&gb[warp][0][0];
    const f32x4* lb1 = (const f32x4*)&gb[warp][1][0];

    // one pipeline step; VM = exact count leaving younger ops in flight
#define PC_BODY(J, B, VMLIT, DO_STAGE)                                         \
    {                                                                          \
        asm volatile("s_waitcnt vmcnt(" #VMLIT ")" ::: "memory");              \
        __builtin_amdgcn_sched_barrier(0);                                     \
        const f32x4* lb = (B) ? lb1 : lb0;                                     \
        f32x4 d0 = lb[ncol * 16 + ((2 * g)     ^ ncol)];                       \
        f32x4 d1 = lb[ncol * 16 + ((2 * g + 1) ^ ncol)];                       \
        f32x4 d2 = lb[ncol * 16 + ((8 + 2 * g) ^ ncol)];                       \
        f32x4 d3 = lb[ncol * 16 + ((9 + 2 * g) ^ ncol)];                       \
        asm volatile("s_waitcnt lgkmcnt(0)" ::: "memory");                     \
        __builtin_amdgcn_sched_barrier(0);                                     \
        if (DO_STAGE) stage((J) + 2, B);                                       \
        bf16x8 A0 = cvt8(tof4(d0), tof4(d1));                                  \
        bf16x8 A1 = cvt8(tof4(d2), tof4(d3));                                  \
        f32x4 acc[4];                                                          \
        _Pragma("unroll")                                                      \
        for (int nt = 0; nt < 4; ++nt) acc[nt] = (f32x4){0.f, 0.f, 0.f, 0.f};  \
        _Pragma("unroll")                                                      \
        for (int nt = 0; nt < 4; ++nt) {                                       \
            acc[nt] = __builtin_amdgcn_mfma_f32_16x16x32_bf16(A0, Bf[nt*2+0], acc[nt], 0, 0, 0); \
            acc[nt] = __builtin_amdgcn_mfma_f32_16x16x32_bf16(A1, Bf[nt*2+1], acc[nt], 0, 0, 0); \
        }                                                                      \
        const int base = tileof(J) * 16;                                       \
        _Pragma("unroll")                                                      \
        for (int r = 0; r < 4; ++r) {                                          \
            f16x4 pk;                                                          \
            _Pragma("unroll")                                                  \
            for (int nt = 0; nt < 4; ++nt) pk[nt] = (_Float16)acc[nt][r];      \
            *(f16x4*)(V + (size_t)(base + g * 4 + r) * 64 + ncol * 4) = pk;    \
        }                                                                      \
    }

    // vmcnt ladder derived from issue queue (glds before stores each iter):
    // j=0: [g0,g1] -> wait g0: 4 ; j=1: [g1,g2,s0] -> 8 ;
    // j=2: [g2,s0,g3,s1] -> 12 ; j=3: [g3,s1,s2] -> 8
    PC_BODY(0, 0, 4,  true)
    PC_BODY(1, 1, 8,  true)
    PC_BODY(2, 0, 12, false)
    PC_BODY(3, 1, 8,  false)
#undef PC_BODY
}

// ---------------- main: gather-sum-tanh-dot over V' ----------------
__global__ __launch_bounds__(THREADS) void etl_main(
    const int*      __restrict__ bi,   // [500000,3]
    const float*    __restrict__ t,    // [500000]
    const _Float16* __restrict__ V,    // [300000,64] permuted cols
    const float*    __restrict__ W1,   // [193,50] (row 192 used)
    const float*    __restrict__ b1,   // [50]
    const float*    __restrict__ W2,   // [50]
    const float*    __restrict__ b2,   // [1]
    float*          __restrict__ out)  // [500000]
{
    const int lane = threadIdx.x & 63;
    const int r8   = lane >> 3;   // 0..7: row within 8-row group
    const int c    = lane & 7;    // 0..7: 8-wide position chunk

    // position pos = c*8+j in V' maps to original col n = (pos&3)*16 + (pos>>2)
    float w192r[8], b1r[8], w2r[8];
#pragma unroll
    for (int j = 0; j < 8; ++j) {
        int pos = c * 8 + j;
        int n = (pos & 3) * 16 + (pos >> 2);
        bool vld = n < 50;
        w192r[j] = vld ? W1[192 * 50 + n] : 0.f;
        b1r[j]   = vld ? b1[n] : 0.f;
        w2r[j]   = vld ? W2[n] : 0.f;
    }
    const float b2v = b2[0];

    const int nwaves = NB_MAIN * (THREADS / 64);
    for (int it = blockIdx.x * (THREADS / 64) + (threadIdx.x >> 6);
         it < NITERS_M; it += nwaves) {
        const int base = it * 32;   // 32 rows per wave-iteration

        int id[4][3];
#pragma unroll
        for (int u = 0; u < 4; ++u) {
            int r = base + u * 8 + r8;
#pragma unroll
            for (int m = 0; m < 3; ++m)
                id[u][m] = bi[r * 3 + m] + m * 100000;
        }

        f16x8 va[4][3];
#pragma unroll
        for (int u = 0; u < 4; ++u)
#pragma unroll
            for (int m = 0; m < 3; ++m)
                va[u][m] = *(const f16x8*)(V + (size_t)id[u][m] * 64 + c * 8);

        float tv[4];
#pragma unroll
        for (int u = 0; u < 4; ++u) tv[u] = t[base + u * 8 + r8];

#pragma unroll
        for (int u = 0; u < 4; ++u) {
            float acc = 0.f;
#pragma unroll
            for (int j = 0; j < 8; ++j) {
                float h = (float)va[u][0][j] + (float)va[u][1][j] +
                          (float)va[u][2][j] + tv[u] * w192r[j] + b1r[j];
                float e = __expf(2.f * h);
                acc += (1.f - 2.f * __builtin_amdgcn_rcpf(e + 1.f)) * w2r[j];
            }
            acc += __shfl_xor(acc, 1, 64);
            acc += __shfl_xor(acc, 2, 64);
            acc += __shfl_xor(acc, 4, 64);
            if (c == 0) out[base + u * 8 + r8] = acc + b2v;
        }
    }
}

// ---------------- fallback: direct f32 gather (ws too small) ----------------
__global__ __launch_bounds__(THREADS) void etl_f32(
    const int*   __restrict__ bi,
    const float* __restrict__ t,
    const float* __restrict__ U,
    const float* __restrict__ W1,
    const float* __restrict__ b1,
    const float* __restrict__ W2,
    const float* __restrict__ b2,
    float*       __restrict__ out)
{
    __shared__ short bsh[24][64][8];
    for (int e = threadIdx.x; e < 24 * 64; e += THREADS) {
        int f = e >> 6, l = e & 63;
        int nt = f / 6, ks = f - nt * 6;
        int n  = nt * 16 + (l & 15);
        int k0 = ks * 32 + ((l >> 4) << 3);
        bf16x8 v;
#pragma unroll
        for (int j = 0; j < 8; ++j) {
            float w = (n < 50) ? W1[(k0 + j) * 50 + n] : 0.f;
            v[j] = f2bf(w);
        }
        *(bf16x8*)(&bsh[f][l][0]) = v;
    }
    __syncthreads();

    const int lane = threadIdx.x & 63;
    const int g    = lane >> 4;
    const int ncol = lane & 15;

    bf16x8 Bf[24];
#pragma unroll
    for (int f = 0; f < 24; ++f) Bf[f] = *(const bf16x8*)(&bsh[f][lane][0]);

    float w192[4], b1r[4], w2r[4];
#pragma unroll
    for (int nt = 0; nt < 4; ++nt) {
        int n = nt * 16 + ncol;
        bool vld = (n < 50);
        w192[nt] = vld ? W1[192 * 50 + n] : 0.f;
        b1r[nt]  = vld ? b1[n] : 0.f;
        w2r[nt]  = vld ? W2[n] : 0.f;
    }
    const float b2v = b2[0];

    const int nwaves = 768 * (THREADS / 64);
    const int wid    = blockIdx.x * (THREADS / 64) + (threadIdx.x >> 6);

    for (int tile = wid; tile < 31250; tile += nwaves) {
        const int base = tile * 16;
        const int row  = base + ncol;
        int i0 = bi[row * 3 + 0];
        int i1 = bi[row * 3 + 1] + 100000;
        int i2 = bi[row * 3 + 2] + 200000;

        bf16x8 A[6];
        const float* p0 = U + (size_t)i0 * 64 + g * 8;
        const float* p1 = U + (size_t)i1 * 64 + g * 8;
        const float* p2 = U + (size_t)i2 * 64 + g * 8;
        A[0] = cvt8(((const float4*)p0)[0], ((const float4*)p0)[1]);
        A[1] = cvt8(((const float4*)(p0 + 32))[0], ((const float4*)(p0 + 32))[1]);
        A[2] = cvt8(((const float4*)p1)[0], ((const float4*)p1)[1]);
        A[3] = cvt8(((const float4*)(p1 + 32))[0], ((const float4*)(p1 + 32))[1]);
        A[4] = cvt8(((const float4*)p2)[0], ((const float4*)p2)[1]);
        A[5] = cvt8(((const float4*)(p2 + 32))[0], ((const float4*)(p2 + 32))[1]);

        f32x4 acc[4];
#pragma unroll
        for (int nt = 0; nt < 4; ++nt) acc[nt] = (f32x4){0.f, 0.f, 0.f, 0.f};
#pragma unroll
        for (int ks = 0; ks < 6; ++ks) {
#pragma unroll
            for (int nt = 0; nt < 4; ++nt) {
                acc[nt] = __builtin_amdgcn_mfma_f32_16x16x32_bf16(
                    A[ks], Bf[nt * 6 + ks], acc[nt], 0, 0, 0);
            }
        }

        float4 tv = *(const float4*)(t + base + g * 4);
        float tarr[4] = {tv.x, tv.y, tv.z, tv.w};
        float part[4] = {0.f, 0.f, 0.f, 0.f};
#pragma unroll
        for (int nt = 0; nt < 4; ++nt) {
#pragma unroll
            for (int r = 0; r < 4; ++r) {
                float pre = acc[nt][r] + tarr[r] * w192[nt] + b1r[nt];
                float e  = __expf(2.f * pre);
                float h  = 1.f - 2.f * __builtin_amdgcn_rcpf(e + 1.f);
                part[r] += h * w2r[nt];
            }
        }
#pragma unroll
        for (int r = 0; r < 4; ++r) {
#pragma unroll
            for (int m = 1; m < 16; m <<= 1)
                part[r] += __shfl_xor(part[r], m, 64);
        }
        if (ncol == 0) {
            float4 o = make_float4(part[0] + b2v, part[1] + b2v,
                                   part[2] + b2v, part[3] + b2v);
            *(float4*)(out + base + g * 4) = o;
        }
    }
}

extern "C" void kernel_launch(void* const* d_in, const int* in_sizes, int n_in,
                              void* d_out, int out_size, void* d_ws, size_t ws_size,
                              hipStream_t stream) {
    const int*   bi = (const int*)  d_in[0];
    const float* t  = (const float*)d_in[1];
    const float* U  = (const float*)d_in[2];
    const float* W1 = (const float*)d_in[3];
    const float* b1 = (const float*)d_in[4];
    const float* W2 = (const float*)d_in[5];
    const float* b2 = (const float*)d_in[6];
    float* out = (float*)d_out;

    if (ws_size >= (size_t)WS_NEED) {
        _Float16* V = (_Float16*)d_ws;
        pc_kernel<<<NB_PC, THREADS, 0, stream>>>(U, W1, V);
        etl_main<<<NB_MAIN, THREADS, 0, stream>>>(bi, t, V, W1, b1, W2, b2, out);
    } else {
        etl_f32<<<768, THREADS, 0, stream>>>(bi, t, U, W1, b1, W2, b2, out);
    }
}